// Round 3
// baseline (311.947 us; speedup 1.0000x reference)
//
#include <hip/hip_runtime.h>
#include <stdint.h>

// Problem constants
#define CC 8
#define NN 1024
#define CN 8192
#define NE 65536
#define NEG_SLOPE 0.2f

typedef __attribute__((ext_vector_type(8))) short bf16x8;
typedef __attribute__((ext_vector_type(4))) float f32x4;

__device__ __forceinline__ ushort f2bfu(float x) {
    unsigned u = __float_as_uint(x);
    unsigned r = u + 0x7fffu + ((u >> 16) & 1u);
    return (ushort)(r >> 16);
}

// ---------------- masks scatter ----------------
__global__ void k_scatter(const int* __restrict__ edges,
                          float* __restrict__ msrc, float* __restrict__ mdst) {
    int e = blockIdx.x * 256 + threadIdx.x;
    if (e < NE) {
        msrc[edges[e]] = 1.0f;
        mdst[edges[NE + e]] = 1.0f;
    }
}

// ---------------- per-type linear: feat[c][t][n][k] = hs[cn,t,:] @ fc[t,:,:] (f32) ----------------
// grid (512, 3): bx&1 = k-half (128 cols), bx>>1 = 32-row block. block 256.
__global__ void __launch_bounds__(256) k_feat(const float* __restrict__ nf,
                                              const float* __restrict__ fc,
                                              float* __restrict__ feat) {
    __shared__ float sFC[64][132];        // fc[i][k-half] f32, padded
    __shared__ float sHT[64][36];         // transposed hs: [i][r] f32
    int t = threadIdx.x;
    int tt = blockIdx.y;
    int kh = blockIdx.x & 1;
    int r0 = (blockIdx.x >> 1) * 32;
    {   // load fc half-plane: 64 x 128 f32
        const float* fcp = fc + tt * 16384 + kh * 128;
        #pragma unroll
        for (int i = 0; i < 8; ++i) {
            int f4 = t + 256 * i;
            int row = f4 >> 5, c4 = f4 & 31;
            *(float4*)&sFC[row][c4 * 4] = *(const float4*)(fcp + row * 256 + c4 * 4);
        }
    }
    {   // load 32 rows x 64 inputs, transpose into sHT
        #pragma unroll
        for (int i = 0; i < 2; ++i) {
            int f4 = t + 256 * i;
            int r = f4 >> 4, c4 = f4 & 15;
            float4 v = *(const float4*)(nf + (size_t)(r0 + r) * 192 + tt * 64 + c4 * 4);
            sHT[c4 * 4 + 0][r] = v.x;
            sHT[c4 * 4 + 1][r] = v.y;
            sHT[c4 * 4 + 2][r] = v.z;
            sHT[c4 * 4 + 3][r] = v.w;
        }
    }
    __syncthreads();
    int rg = t >> 5;        // rows rg*4..+4
    int kg = t & 31;        // cols kg*4..+4 (of this 128 half)
    float acc[4][4];
    #pragma unroll
    for (int a = 0; a < 4; ++a)
        #pragma unroll
        for (int b = 0; b < 4; ++b) acc[a][b] = 0.f;
    #pragma unroll 4
    for (int i = 0; i < 64; ++i) {
        float4 hv = *(const float4*)&sHT[i][rg * 4];
        float4 fv = *(const float4*)&sFC[i][kg * 4];
        const float* fp = (const float*)&fv;
        #pragma unroll
        for (int b = 0; b < 4; ++b) {
            acc[0][b] += hv.x * fp[b];
            acc[1][b] += hv.y * fp[b];
            acc[2][b] += hv.z * fp[b];
            acc[3][b] += hv.w * fp[b];
        }
    }
    #pragma unroll
    for (int a = 0; a < 4; ++a) {
        int b = r0 + rg * 4 + a;
        int c = b >> 10, n = b & 1023;
        float4 vv = {acc[a][0], acc[a][1], acc[a][2], acc[a][3]};
        *(float4*)(feat + (size_t)c * 786432 + (size_t)tt * 262144 + n * 256 + kh * 128 + kg * 4) = vv;
    }
}

// ---------------- remap + masks + attention logit partials + fd(bf16) ----------------
// grid 8192 (c*1024+n2), block 256.  thread t: h=t>>6 (wave id), f=t&63
__global__ void __launch_bounds__(256) k_remap(const float* __restrict__ feat,
                        const float* __restrict__ attn_src, const float* __restrict__ attn_dst,
                        const float* __restrict__ msrc, const float* __restrict__ mdst,
                        ushort* __restrict__ fd, float* __restrict__ a_src, float* __restrict__ a_dst) {
    int b = blockIdx.x;
    int c = b >> 10, n2 = b & 1023;
    int t = threadIdx.x;
    int h = t >> 6, f = t & 63;
    float md = mdst[b], ms = msrc[b];
    const float* fp = feat + (size_t)c * 786432 + (size_t)n2 * 768;
    float ssum = 0.f, dsum = 0.f;
    #pragma unroll
    for (int t2 = 0; t2 < 3; ++t2) {
        float val = fp[t2 * 256 + t];
        int j = t2 * 64 + f;
        ssum += val * attn_src[h * 192 + j];
        dsum += val * attn_dst[h * 192 + j];
        fd[((size_t)(c * 4 + h) * 1024 + n2) * 192 + j] = f2bfu(val * md);
    }
    #pragma unroll
    for (int o = 32; o > 0; o >>= 1) {
        ssum += __shfl_down(ssum, o, 64);
        dsum += __shfl_down(dsum, o, 64);
    }
    if (f == 0) {
        a_src[(b << 2) + h] = ssum * ms;
        a_dst[(b << 2) + h] = dsum * md;
    }
}

// ---------------- transpose fd[ch][u][j] -> fdt[ch][j][u] (bf16) ----------------
// grid (16 u-tiles, 3 j-tiles, 32 ch), block 256, 64x64 tiles
__global__ void k_trans(const ushort* __restrict__ fd, ushort* __restrict__ fdt) {
    __shared__ ushort tile[64][68];
    int ch = blockIdx.z;
    int u0 = blockIdx.x * 64, j0 = blockIdx.y * 64;
    int t = threadIdx.x;
    const ushort* src = fd + (size_t)ch * (1024 * 192) + (size_t)u0 * 192 + j0;
    #pragma unroll
    for (int i = 0; i < 2; ++i) {
        int vid = t + 256 * i;
        int r = vid >> 3, ccol = (vid & 7) * 8;
        uint4 v = *(const uint4*)(src + (size_t)r * 192 + ccol);
        const ushort* us = (const ushort*)&v;
        #pragma unroll
        for (int jj = 0; jj < 8; ++jj) tile[r][ccol + jj] = us[jj];
    }
    __syncthreads();
    ushort* dst = fdt + (size_t)ch * (192 * 1024) + (size_t)j0 * 1024 + u0;
    #pragma unroll
    for (int i = 0; i < 2; ++i) {
        int vid = t + 256 * i;
        int jr = vid >> 3, uc = (vid & 7) * 8;
        ushort tmp[8];
        #pragma unroll
        for (int jj = 0; jj < 8; ++jj) tmp[jj] = tile[uc + jj][jr];
        *(uint4*)(dst + (size_t)jr * 1024 + uc) = *(const uint4*)tmp;
    }
}

// ---------------- attention + softmax over c; writes a (f32, d_out) and Abuf[ch][v][u] bf16 ----------------
// grid (1024 v, 2 u-chunks), block 256; thread handles u0 = chunk*512 + t*2 and u0+1
// 3-pass recompute softmax: no per-thread logit array -> no scratch spill.
// Output stores are NONTEMPORAL (ext-vector f32x4 / unsigned for builtin legality):
// a_out is never re-read on device; Abuf (67MB) can't fit L2 anyway.
__global__ void __launch_bounds__(256) k_att(const float* __restrict__ a_src,
                                             const float* __restrict__ a_dst,
                                             float* __restrict__ a_out, ushort* __restrict__ Abuf) {
    __shared__ float sAS[32];
    int v = blockIdx.x;
    int t = threadIdx.x;
    if (t < 32) sAS[t] = a_src[((t >> 2) * 1024 + v) * 4 + (t & 3)];
    __syncthreads();
    int u0 = blockIdx.y * 512 + t * 2;

    // ---- pass 1: raw max over c (leaky/clip applied once afterwards) ----
    float mx0[4], mx1[4];
    #pragma unroll
    for (int h = 0; h < 4; ++h) { mx0[h] = -1e30f; mx1[h] = -1e30f; }
    #pragma unroll
    for (int c = 0; c < 8; ++c) {
        float4 d0 = *(const float4*)(a_dst + ((c << 10) + u0) * 4);
        float4 d1 = *(const float4*)(a_dst + ((c << 10) + u0 + 1) * 4);
        const float* dp0 = (const float*)&d0;
        const float* dp1 = (const float*)&d1;
        #pragma unroll
        for (int h = 0; h < 4; ++h) {
            float as = sAS[c * 4 + h];
            mx0[h] = fmaxf(mx0[h], as + dp0[h]);
            mx1[h] = fmaxf(mx1[h], as + dp1[h]);
        }
    }
    #pragma unroll
    for (int h = 0; h < 4; ++h) {
        float x = mx0[h];
        x = (x >= 0.f) ? x : NEG_SLOPE * x;
        mx0[h] = fminf(fmaxf(x, -1e9f), 1e9f);
        float y = mx1[h];
        y = (y >= 0.f) ? y : NEG_SLOPE * y;
        mx1[h] = fminf(fmaxf(y, -1e9f), 1e9f);
    }

    // ---- pass 2: recompute logits, accumulate exp sums ----
    float s0[4] = {0.f, 0.f, 0.f, 0.f}, s1[4] = {0.f, 0.f, 0.f, 0.f};
    #pragma unroll
    for (int c = 0; c < 8; ++c) {
        float4 d0 = *(const float4*)(a_dst + ((c << 10) + u0) * 4);
        float4 d1 = *(const float4*)(a_dst + ((c << 10) + u0 + 1) * 4);
        const float* dp0 = (const float*)&d0;
        const float* dp1 = (const float*)&d1;
        #pragma unroll
        for (int h = 0; h < 4; ++h) {
            float as = sAS[c * 4 + h];
            float x = as + dp0[h];
            x = (x >= 0.f) ? x : NEG_SLOPE * x;
            x = fminf(fmaxf(x, -1e9f), 1e9f);
            s0[h] += __expf(x - mx0[h]);
            float y = as + dp1[h];
            y = (y >= 0.f) ? y : NEG_SLOPE * y;
            y = fminf(fmaxf(y, -1e9f), 1e9f);
            s1[h] += __expf(y - mx1[h]);
        }
    }
    float r0[4], r1[4];
    #pragma unroll
    for (int h = 0; h < 4; ++h) { r0[h] = 1.f / s0[h]; r1[h] = 1.f / s1[h]; }

    // ---- pass 3: recompute, normalize, write a_out (f32,nt) + Abuf (bf16,nt) ----
    #pragma unroll
    for (int c = 0; c < 8; ++c) {
        float4 d0 = *(const float4*)(a_dst + ((c << 10) + u0) * 4);
        float4 d1 = *(const float4*)(a_dst + ((c << 10) + u0 + 1) * 4);
        const float* dp0 = (const float*)&d0;
        const float* dp1 = (const float*)&d1;
        f32x4 w0, w1;
        unsigned packs[4];
        #pragma unroll
        for (int h = 0; h < 4; ++h) {
            float as = sAS[c * 4 + h];
            float x = as + dp0[h];
            x = (x >= 0.f) ? x : NEG_SLOPE * x;
            x = fminf(fmaxf(x, -1e9f), 1e9f);
            float p0 = __expf(x - mx0[h]) * r0[h];
            float y = as + dp1[h];
            y = (y >= 0.f) ? y : NEG_SLOPE * y;
            y = fminf(fmaxf(y, -1e9f), 1e9f);
            float p1 = __expf(y - mx1[h]) * r1[h];
            w0[h] = p0; w1[h] = p1;
            packs[h] = (unsigned)f2bfu(p0) | ((unsigned)f2bfu(p1) << 16);
        }
        float* ao = a_out + ((size_t)((c << 10) + v) * 1024 + u0) * 4;
        __builtin_nontemporal_store(w0, (f32x4*)ao);
        __builtin_nontemporal_store(w1, (f32x4*)ao + 1);
        #pragma unroll
        for (int h = 0; h < 4; ++h)
            __builtin_nontemporal_store(packs[h],
                (unsigned*)(Abuf + (size_t)((c * 4 + h) * 1024 + v) * 1024 + u0));
    }
}

// ---------------- GEMM per (c,h): M[v][j] = sum_u A[v][u] * fdt[j][u] ----------------
// grid (8 v-tiles, 32 ch), block 256 (4 waves).  BM=128, BN=192, BK=64. mfma 16x16x32 bf16.
__global__ void __launch_bounds__(256) k_gemm(const ushort* __restrict__ A,
                                              const ushort* __restrict__ B,
                                              float* __restrict__ Mout) {
    __shared__ ushort sA[128 * 72];
    __shared__ ushort sB[192 * 72];
    int ch = blockIdx.y;
    int v0 = blockIdx.x * 128;
    int t = threadIdx.x;
    const ushort* pA = A + (size_t)ch * (1024 * 1024) + (size_t)v0 * 1024;
    const ushort* pB = B + (size_t)ch * (192 * 1024);
    int wid = t >> 6, lane = t & 63;
    int wm = (wid & 1) * 64, wn = (wid >> 1) * 96;
    int lm = lane & 15, lq = lane >> 4;
    f32x4 acc[4][6];
    #pragma unroll
    for (int i = 0; i < 4; ++i)
        #pragma unroll
        for (int j = 0; j < 6; ++j)
            acc[i][j] = (f32x4){0.f, 0.f, 0.f, 0.f};
    for (int kk = 0; kk < 1024; kk += 64) {
        #pragma unroll
        for (int i = 0; i < 4; ++i) {
            int cid = t + 256 * i;
            int r = cid >> 3, kc = cid & 7;
            uint4 vv = *(const uint4*)(pA + (size_t)r * 1024 + kk + kc * 8);
            *(uint4*)&sA[r * 72 + kc * 8] = vv;
        }
        #pragma unroll
        for (int i = 0; i < 6; ++i) {
            int cid = t + 256 * i;
            int r = cid >> 3, kc = cid & 7;
            uint4 vv = *(const uint4*)(pB + (size_t)r * 1024 + kk + kc * 8);
            *(uint4*)&sB[r * 72 + kc * 8] = vv;
        }
        __syncthreads();
        #pragma unroll
        for (int ks = 0; ks < 64; ks += 32) {
            bf16x8 af[4], bg[6];
            #pragma unroll
            for (int i = 0; i < 4; ++i)
                af[i] = *(const bf16x8*)&sA[(wm + i * 16 + lm) * 72 + ks + lq * 8];
            #pragma unroll
            for (int j = 0; j < 6; ++j)
                bg[j] = *(const bf16x8*)&sB[(wn + j * 16 + lm) * 72 + ks + lq * 8];
            #pragma unroll
            for (int i = 0; i < 4; ++i)
                #pragma unroll
                for (int j = 0; j < 6; ++j)
                    acc[i][j] = __builtin_amdgcn_mfma_f32_16x16x32_bf16(af[i], bg[j], acc[i][j], 0, 0, 0);
        }
        __syncthreads();
    }
    float* pM = Mout + (size_t)ch * 196608 + (size_t)v0 * 192;
    #pragma unroll
    for (int i = 0; i < 4; ++i)
        #pragma unroll
        for (int r = 0; r < 4; ++r) {
            int row = wm + i * 16 + lq * 4 + r;
            #pragma unroll
            for (int j = 0; j < 6; ++j)
                pM[(size_t)row * 192 + wn + j * 16 + lm] = acc[i][j][r];
        }
}

// ---------------- epilogue: outs[c][v][tf] = sum_h relu(M[ch][v][tf]) (f32) ----------------
__global__ void k_out(const float* __restrict__ Mm, float* __restrict__ outp) {
    int b = blockIdx.x;
    int c = b >> 10, v = b & 1023;
    int tf = threadIdx.x;
    float s = 0.f;
    #pragma unroll
    for (int h = 0; h < 4; ++h) {
        float x = Mm[(size_t)(c * 4 + h) * 196608 + (size_t)v * 192 + tf];
        s += fmaxf(x, 0.f);
    }
    outp[(size_t)b * 192 + tf] = s;
}

extern "C" void kernel_launch(void* const* d_in, const int* in_sizes, int n_in,
                              void* d_out, int out_size, void* d_ws, size_t ws_size,
                              hipStream_t stream) {
    const int*   edges  = (const int*)d_in[0];
    const float* nf     = (const float*)d_in[1];
    const float* fc     = (const float*)d_in[2];
    const float* asrc_w = (const float*)d_in[3];
    const float* adst_w = (const float*)d_in[4];
    float* outp  = (float*)d_out;
    float* a_out = outp + 1572864;     // outs (1,572,864 f32) then a (33,554,432 f32)

    char* ws = (char*)d_ws;
    float*  msrc  = (float*)(ws + 0);            // 32 KB
    float*  mdst  = (float*)(ws + 32768);        // 32 KB
    float*  a_src = (float*)(ws + 65536);        // 128 KB
    float*  a_dst = (float*)(ws + 196608);       // 128 KB
    ushort* fdt   = (ushort*)(ws + 327680);      // 12.58 MB bf16
    float*  feat  = (float*)(ws + 12910592);     // 25.17 MB f32 (aliased with Mm)
    float*  Mm    = feat;                        // feat dead after k_remap
    ushort* Abuf  = (ushort*)(ws + 38076416);    // 67.1 MB bf16
    ushort* fd    = Abuf;                        // fd dead after k_trans, before k_att writes Abuf

    hipMemsetAsync(msrc, 0, 65536, stream);      // zero both masks
    k_scatter<<<dim3(256), dim3(256), 0, stream>>>(edges, msrc, mdst);
    k_feat<<<dim3(512, 3), dim3(256), 0, stream>>>(nf, fc, feat);
    k_remap<<<dim3(8192), dim3(256), 0, stream>>>(feat, asrc_w, adst_w, msrc, mdst, fd, a_src, a_dst);
    k_trans<<<dim3(16, 3, 32), dim3(256), 0, stream>>>(fd, fdt);
    k_att<<<dim3(1024, 2), dim3(256), 0, stream>>>(a_src, a_dst, a_out, Abuf);
    k_gemm<<<dim3(8, 32), dim3(256), 0, stream>>>(Abuf, fdt, Mm);
    k_out<<<dim3(8192), dim3(192), 0, stream>>>(Mm, outp);
}

// Round 4
// 298.538 us; speedup vs baseline: 1.0449x; 1.0449x over previous
//
#include <hip/hip_runtime.h>
#include <stdint.h>

// Problem constants
#define CC 8
#define NN 1024
#define CN 8192
#define NE 65536
#define NEG_SLOPE 0.2f

typedef __attribute__((ext_vector_type(8))) short bf16x8;
typedef __attribute__((ext_vector_type(4))) float f32x4;

__device__ __forceinline__ ushort f2bfu(float x) {
    unsigned u = __float_as_uint(x);
    unsigned r = u + 0x7fffu + ((u >> 16) & 1u);
    return (ushort)(r >> 16);
}

// ---------------- masks scatter ----------------
__global__ void k_scatter(const int* __restrict__ edges,
                          float* __restrict__ msrc, float* __restrict__ mdst) {
    int e = blockIdx.x * 256 + threadIdx.x;
    if (e < NE) {
        msrc[edges[e]] = 1.0f;
        mdst[edges[NE + e]] = 1.0f;
    }
}

// ---------------- per-type linear: feat[c][t][n][k] = hs[cn,t,:] @ fc[t,:,:] (f32) ----------------
// grid (512, 3): bx&1 = k-half (128 cols), bx>>1 = 32-row block. block 256.
__global__ void __launch_bounds__(256) k_feat(const float* __restrict__ nf,
                                              const float* __restrict__ fc,
                                              float* __restrict__ feat) {
    __shared__ float sFC[64][132];        // fc[i][k-half] f32, padded
    __shared__ float sHT[64][36];         // transposed hs: [i][r] f32
    int t = threadIdx.x;
    int tt = blockIdx.y;
    int kh = blockIdx.x & 1;
    int r0 = (blockIdx.x >> 1) * 32;
    {   // load fc half-plane: 64 x 128 f32
        const float* fcp = fc + tt * 16384 + kh * 128;
        #pragma unroll
        for (int i = 0; i < 8; ++i) {
            int f4 = t + 256 * i;
            int row = f4 >> 5, c4 = f4 & 31;
            *(float4*)&sFC[row][c4 * 4] = *(const float4*)(fcp + row * 256 + c4 * 4);
        }
    }
    {   // load 32 rows x 64 inputs, transpose into sHT
        #pragma unroll
        for (int i = 0; i < 2; ++i) {
            int f4 = t + 256 * i;
            int r = f4 >> 4, c4 = f4 & 15;
            float4 v = *(const float4*)(nf + (size_t)(r0 + r) * 192 + tt * 64 + c4 * 4);
            sHT[c4 * 4 + 0][r] = v.x;
            sHT[c4 * 4 + 1][r] = v.y;
            sHT[c4 * 4 + 2][r] = v.z;
            sHT[c4 * 4 + 3][r] = v.w;
        }
    }
    __syncthreads();
    int rg = t >> 5;        // rows rg*4..+4
    int kg = t & 31;        // cols kg*4..+4 (of this 128 half)
    float acc[4][4];
    #pragma unroll
    for (int a = 0; a < 4; ++a)
        #pragma unroll
        for (int b = 0; b < 4; ++b) acc[a][b] = 0.f;
    #pragma unroll 4
    for (int i = 0; i < 64; ++i) {
        float4 hv = *(const float4*)&sHT[i][rg * 4];
        float4 fv = *(const float4*)&sFC[i][kg * 4];
        const float* fp = (const float*)&fv;
        #pragma unroll
        for (int b = 0; b < 4; ++b) {
            acc[0][b] += hv.x * fp[b];
            acc[1][b] += hv.y * fp[b];
            acc[2][b] += hv.z * fp[b];
            acc[3][b] += hv.w * fp[b];
        }
    }
    #pragma unroll
    for (int a = 0; a < 4; ++a) {
        int b = r0 + rg * 4 + a;
        int c = b >> 10, n = b & 1023;
        float4 vv = {acc[a][0], acc[a][1], acc[a][2], acc[a][3]};
        *(float4*)(feat + (size_t)c * 786432 + (size_t)tt * 262144 + n * 256 + kh * 128 + kg * 4) = vv;
    }
}

// ---------------- fused remap + transpose ----------------
// grid (32 u-tiles, 8 c, 3 t2), block 256.  thread t: h=t>>6 (wave id), f=t&63, j=t2*64+f.
// Per block: 32 nodes, one t2-slice. Writes fdt[ch][j][u] directly (transposed via LDS tile);
// attention logit partials accumulated with atomicAdd (a_src/a_dst zeroed by host memset).
__global__ void __launch_bounds__(256) k_remap2(const float* __restrict__ feat,
                        const float* __restrict__ attn_src, const float* __restrict__ attn_dst,
                        const float* __restrict__ msrc, const float* __restrict__ mdst,
                        ushort* __restrict__ fdt, float* __restrict__ a_src, float* __restrict__ a_dst) {
    __shared__ ushort T[4 * 64 * 34];     // [h][j_local 64][u 32 + 2 pad] bf16, 17.4 KB
    int u0 = blockIdx.x * 32;
    int c  = blockIdx.y;
    int t2 = blockIdx.z;
    int t = threadIdx.x;
    int h = t >> 6, f = t & 63;
    float aw_s = attn_src[h * 192 + t2 * 64 + f];
    float aw_d = attn_dst[h * 192 + t2 * 64 + f];
    const float* fbase = feat + (size_t)c * 786432 + (size_t)u0 * 768 + t2 * 256 + t;
    for (int n = 0; n < 32; ++n) {
        int b = (c << 10) + u0 + n;
        float md = mdst[b];
        float val = fbase[(size_t)n * 768];
        float ssum = val * aw_s, dsum = val * aw_d;
        T[(h * 64 + f) * 34 + n] = f2bfu(val * md);
        #pragma unroll
        for (int o = 32; o > 0; o >>= 1) {
            ssum += __shfl_down(ssum, o, 64);
            dsum += __shfl_down(dsum, o, 64);
        }
        if (f == 0) {
            atomicAdd(&a_src[(b << 2) + h], ssum * msrc[b]);
            atomicAdd(&a_dst[(b << 2) + h], dsum * md);
        }
    }
    __syncthreads();
    // write fdt: 256 rows (4h x 64 j_local) x 32 u; 4 uint4 chunks per thread.
    #pragma unroll
    for (int i = 0; i < 4; ++i) {
        int id = t + 256 * i;          // 0..1023
        int row = id >> 2;             // 0..255: h2 = row>>6, jl = row&63
        int cu = (id & 3) * 8;         // u offset within tile
        int base = row * 34 + cu;      // ushort index into T (4-byte aligned)
        uint w0 = *(const uint*)&T[base + 0];
        uint w1 = *(const uint*)&T[base + 2];
        uint w2 = *(const uint*)&T[base + 4];
        uint w3 = *(const uint*)&T[base + 6];
        uint4 vv = {w0, w1, w2, w3};
        int h2 = row >> 6, jl = row & 63;
        int ch = (c << 2) + h2;
        int jj = t2 * 64 + jl;
        *(uint4*)(fdt + (size_t)ch * 196608 + (size_t)jj * 1024 + u0 + cu) = vv;
    }
}

// ---------------- attention + softmax over c; writes a (f32, d_out) and Abuf[ch][v][u] bf16 ----------------
// grid (1024 v, 2 u-chunks), block 256; thread handles u0 = chunk*512 + t*2 and u0+1
// 3-pass recompute softmax: no per-thread logit array -> no scratch spill.
__global__ void __launch_bounds__(256) k_att(const float* __restrict__ a_src,
                                             const float* __restrict__ a_dst,
                                             float* __restrict__ a_out, ushort* __restrict__ Abuf) {
    __shared__ float sAS[32];
    int v = blockIdx.x;
    int t = threadIdx.x;
    if (t < 32) sAS[t] = a_src[((t >> 2) * 1024 + v) * 4 + (t & 3)];
    __syncthreads();
    int u0 = blockIdx.y * 512 + t * 2;

    // ---- pass 1: raw max over c (leaky/clip applied once afterwards) ----
    float mx0[4], mx1[4];
    #pragma unroll
    for (int h = 0; h < 4; ++h) { mx0[h] = -1e30f; mx1[h] = -1e30f; }
    #pragma unroll
    for (int c = 0; c < 8; ++c) {
        float4 d0 = *(const float4*)(a_dst + ((c << 10) + u0) * 4);
        float4 d1 = *(const float4*)(a_dst + ((c << 10) + u0 + 1) * 4);
        const float* dp0 = (const float*)&d0;
        const float* dp1 = (const float*)&d1;
        #pragma unroll
        for (int h = 0; h < 4; ++h) {
            float as = sAS[c * 4 + h];
            mx0[h] = fmaxf(mx0[h], as + dp0[h]);
            mx1[h] = fmaxf(mx1[h], as + dp1[h]);
        }
    }
    #pragma unroll
    for (int h = 0; h < 4; ++h) {
        float x = mx0[h];
        x = (x >= 0.f) ? x : NEG_SLOPE * x;
        mx0[h] = fminf(fmaxf(x, -1e9f), 1e9f);
        float y = mx1[h];
        y = (y >= 0.f) ? y : NEG_SLOPE * y;
        mx1[h] = fminf(fmaxf(y, -1e9f), 1e9f);
    }

    // ---- pass 2: recompute logits, accumulate exp sums ----
    float s0[4] = {0.f, 0.f, 0.f, 0.f}, s1[4] = {0.f, 0.f, 0.f, 0.f};
    #pragma unroll
    for (int c = 0; c < 8; ++c) {
        float4 d0 = *(const float4*)(a_dst + ((c << 10) + u0) * 4);
        float4 d1 = *(const float4*)(a_dst + ((c << 10) + u0 + 1) * 4);
        const float* dp0 = (const float*)&d0;
        const float* dp1 = (const float*)&d1;
        #pragma unroll
        for (int h = 0; h < 4; ++h) {
            float as = sAS[c * 4 + h];
            float x = as + dp0[h];
            x = (x >= 0.f) ? x : NEG_SLOPE * x;
            x = fminf(fmaxf(x, -1e9f), 1e9f);
            s0[h] += __expf(x - mx0[h]);
            float y = as + dp1[h];
            y = (y >= 0.f) ? y : NEG_SLOPE * y;
            y = fminf(fmaxf(y, -1e9f), 1e9f);
            s1[h] += __expf(y - mx1[h]);
        }
    }
    float r0[4], r1[4];
    #pragma unroll
    for (int h = 0; h < 4; ++h) { r0[h] = 1.f / s0[h]; r1[h] = 1.f / s1[h]; }

    // ---- pass 3: recompute, normalize, write a_out (f32) + Abuf (bf16) ----
    #pragma unroll
    for (int c = 0; c < 8; ++c) {
        float4 d0 = *(const float4*)(a_dst + ((c << 10) + u0) * 4);
        float4 d1 = *(const float4*)(a_dst + ((c << 10) + u0 + 1) * 4);
        const float* dp0 = (const float*)&d0;
        const float* dp1 = (const float*)&d1;
        float w0[4], w1[4];
        unsigned packs[4];
        #pragma unroll
        for (int h = 0; h < 4; ++h) {
            float as = sAS[c * 4 + h];
            float x = as + dp0[h];
            x = (x >= 0.f) ? x : NEG_SLOPE * x;
            x = fminf(fmaxf(x, -1e9f), 1e9f);
            float p0 = __expf(x - mx0[h]) * r0[h];
            float y = as + dp1[h];
            y = (y >= 0.f) ? y : NEG_SLOPE * y;
            y = fminf(fmaxf(y, -1e9f), 1e9f);
            float p1 = __expf(y - mx1[h]) * r1[h];
            w0[h] = p0; w1[h] = p1;
            packs[h] = (unsigned)f2bfu(p0) | ((unsigned)f2bfu(p1) << 16);
        }
        float* ao = a_out + ((size_t)((c << 10) + v) * 1024 + u0) * 4;
        *(float4*)ao = *(const float4*)w0;
        *((float4*)ao + 1) = *(const float4*)w1;
        #pragma unroll
        for (int h = 0; h < 4; ++h)
            *(unsigned*)(Abuf + (size_t)((c * 4 + h) * 1024 + v) * 1024 + u0) = packs[h];
    }
}

// ---------------- GEMM per (c,h): M[v][j] = sum_u A[v][u] * fdt[j][u] ----------------
// grid (8, 32) = 256 blocks, block 256 (4 waves).  BM=128, BN=192, BK=64. mfma 16x16x32 bf16.
// XCD-aware remap: all 8 v-tiles of one ch land on the same XCD (flat%8), so the shared
// B panel (393 KB) stays in that XCD's L2 instead of being re-fetched from L3 8x.
__global__ void __launch_bounds__(256) k_gemm(const ushort* __restrict__ A,
                                              const ushort* __restrict__ B,
                                              float* __restrict__ Mout) {
    __shared__ ushort sA[128 * 72];
    __shared__ ushort sB[192 * 72];
    int flat = blockIdx.y * 8 + blockIdx.x;        // dispatch order
    int ch = (flat >> 6) * 8 + (flat & 7);         // bijective remap
    int v0 = ((flat >> 3) & 7) * 128;
    int t = threadIdx.x;
    const ushort* pA = A + (size_t)ch * (1024 * 1024) + (size_t)v0 * 1024;
    const ushort* pB = B + (size_t)ch * (192 * 1024);
    int wid = t >> 6, lane = t & 63;
    int wm = (wid & 1) * 64, wn = (wid >> 1) * 96;
    int lm = lane & 15, lq = lane >> 4;
    f32x4 acc[4][6];
    #pragma unroll
    for (int i = 0; i < 4; ++i)
        #pragma unroll
        for (int j = 0; j < 6; ++j)
            acc[i][j] = (f32x4){0.f, 0.f, 0.f, 0.f};
    for (int kk = 0; kk < 1024; kk += 64) {
        #pragma unroll
        for (int i = 0; i < 4; ++i) {
            int cid = t + 256 * i;
            int r = cid >> 3, kc = cid & 7;
            uint4 vv = *(const uint4*)(pA + (size_t)r * 1024 + kk + kc * 8);
            *(uint4*)&sA[r * 72 + kc * 8] = vv;
        }
        #pragma unroll
        for (int i = 0; i < 6; ++i) {
            int cid = t + 256 * i;
            int r = cid >> 3, kc = cid & 7;
            uint4 vv = *(const uint4*)(pB + (size_t)r * 1024 + kk + kc * 8);
            *(uint4*)&sB[r * 72 + kc * 8] = vv;
        }
        __syncthreads();
        #pragma unroll
        for (int ks = 0; ks < 64; ks += 32) {
            bf16x8 af[4], bg[6];
            #pragma unroll
            for (int i = 0; i < 4; ++i)
                af[i] = *(const bf16x8*)&sA[(wm + i * 16 + lm) * 72 + ks + lq * 8];
            #pragma unroll
            for (int j = 0; j < 6; ++j)
                bg[j] = *(const bf16x8*)&sB[(wn + j * 16 + lm) * 72 + ks + lq * 8];
            #pragma unroll
            for (int i = 0; i < 4; ++i)
                #pragma unroll
                for (int j = 0; j < 6; ++j)
                    acc[i][j] = __builtin_amdgcn_mfma_f32_16x16x32_bf16(af[i], bg[j], acc[i][j], 0, 0, 0);
        }
        __syncthreads();
    }
    float* pM = Mout + (size_t)ch * 196608 + (size_t)v0 * 192;
    #pragma unroll
    for (int i = 0; i < 4; ++i)
        #pragma unroll
        for (int r = 0; r < 4; ++r) {
            int row = wm + i * 16 + lq * 4 + r;
            #pragma unroll
            for (int j = 0; j < 6; ++j)
                pM[(size_t)row * 192 + wn + j * 16 + lm] = acc[i][j][r];
        }
}

// ---------------- epilogue: outs[c][v][tf] = sum_h relu(M[ch][v][tf]) (f32) ----------------
__global__ void k_out(const float* __restrict__ Mm, float* __restrict__ outp) {
    int b = blockIdx.x;
    int c = b >> 10, v = b & 1023;
    int tf = threadIdx.x;
    float s = 0.f;
    #pragma unroll
    for (int h = 0; h < 4; ++h) {
        float x = Mm[(size_t)(c * 4 + h) * 196608 + (size_t)v * 192 + tf];
        s += fmaxf(x, 0.f);
    }
    outp[(size_t)b * 192 + tf] = s;
}

extern "C" void kernel_launch(void* const* d_in, const int* in_sizes, int n_in,
                              void* d_out, int out_size, void* d_ws, size_t ws_size,
                              hipStream_t stream) {
    const int*   edges  = (const int*)d_in[0];
    const float* nf     = (const float*)d_in[1];
    const float* fc     = (const float*)d_in[2];
    const float* asrc_w = (const float*)d_in[3];
    const float* adst_w = (const float*)d_in[4];
    float* outp  = (float*)d_out;
    float* a_out = outp + 1572864;     // outs (1,572,864 f32) then a (33,554,432 f32)

    char* ws = (char*)d_ws;
    float*  msrc  = (float*)(ws + 0);            // 32 KB
    float*  mdst  = (float*)(ws + 32768);        // 32 KB
    float*  a_src = (float*)(ws + 65536);        // 128 KB (atomic-accumulated)
    float*  a_dst = (float*)(ws + 196608);       // 128 KB (atomic-accumulated)
    ushort* fdt   = (ushort*)(ws + 327680);      // 12.58 MB bf16
    float*  feat  = (float*)(ws + 12910592);     // 25.17 MB f32 (aliased with Mm)
    float*  Mm    = feat;                        // feat dead after k_remap2
    ushort* Abuf  = (ushort*)(ws + 38076416);    // 67.1 MB bf16

    hipMemsetAsync(msrc, 0, 327680, stream);     // zero masks + a_src + a_dst
    k_scatter<<<dim3(256), dim3(256), 0, stream>>>(edges, msrc, mdst);
    k_feat<<<dim3(512, 3), dim3(256), 0, stream>>>(nf, fc, feat);
    k_remap2<<<dim3(32, 8, 3), dim3(256), 0, stream>>>(feat, asrc_w, adst_w, msrc, mdst, fdt, a_src, a_dst);
    k_att<<<dim3(1024, 2), dim3(256), 0, stream>>>(a_src, a_dst, a_out, Abuf);
    k_gemm<<<dim3(8, 32), dim3(256), 0, stream>>>(Abuf, fdt, Mm);
    k_out<<<dim3(8192), dim3(192), 0, stream>>>(Mm, outp);
}

// Round 5
// 282.796 us; speedup vs baseline: 1.1031x; 1.0557x over previous
//
#include <hip/hip_runtime.h>
#include <stdint.h>

// Problem constants
#define CC 8
#define NN 1024
#define CN 8192
#define NE 65536
#define NEG_SLOPE 0.2f

typedef __attribute__((ext_vector_type(8))) short bf16x8;
typedef __attribute__((ext_vector_type(4))) float f32x4;

__device__ __forceinline__ ushort f2bfu(float x) {
    unsigned u = __float_as_uint(x);
    unsigned r = u + 0x7fffu + ((u >> 16) & 1u);
    return (ushort)(r >> 16);
}

// ---------------- masks scatter ----------------
__global__ void k_scatter(const int* __restrict__ edges,
                          float* __restrict__ msrc, float* __restrict__ mdst) {
    int e = blockIdx.x * 256 + threadIdx.x;
    if (e < NE) {
        msrc[edges[e]] = 1.0f;
        mdst[edges[NE + e]] = 1.0f;
    }
}

// ---------------- per-type linear: feat[c][t][n][k] = hs[cn,t,:] @ fc[t,:,:] (f32) ----------------
// grid (512, 3): bx&1 = k-half (128 cols), bx>>1 = 32-row block. block 256.
__global__ void __launch_bounds__(256) k_feat(const float* __restrict__ nf,
                                              const float* __restrict__ fc,
                                              float* __restrict__ feat) {
    __shared__ float sFC[64][132];        // fc[i][k-half] f32, padded
    __shared__ float sHT[64][36];         // transposed hs: [i][r] f32
    int t = threadIdx.x;
    int tt = blockIdx.y;
    int kh = blockIdx.x & 1;
    int r0 = (blockIdx.x >> 1) * 32;
    {   // load fc half-plane: 64 x 128 f32
        const float* fcp = fc + tt * 16384 + kh * 128;
        #pragma unroll
        for (int i = 0; i < 8; ++i) {
            int f4 = t + 256 * i;
            int row = f4 >> 5, c4 = f4 & 31;
            *(float4*)&sFC[row][c4 * 4] = *(const float4*)(fcp + row * 256 + c4 * 4);
        }
    }
    {   // load 32 rows x 64 inputs, transpose into sHT
        #pragma unroll
        for (int i = 0; i < 2; ++i) {
            int f4 = t + 256 * i;
            int r = f4 >> 4, c4 = f4 & 15;
            float4 v = *(const float4*)(nf + (size_t)(r0 + r) * 192 + tt * 64 + c4 * 4);
            sHT[c4 * 4 + 0][r] = v.x;
            sHT[c4 * 4 + 1][r] = v.y;
            sHT[c4 * 4 + 2][r] = v.z;
            sHT[c4 * 4 + 3][r] = v.w;
        }
    }
    __syncthreads();
    int rg = t >> 5;        // rows rg*4..+4
    int kg = t & 31;        // cols kg*4..+4 (of this 128 half)
    float acc[4][4];
    #pragma unroll
    for (int a = 0; a < 4; ++a)
        #pragma unroll
        for (int b = 0; b < 4; ++b) acc[a][b] = 0.f;
    #pragma unroll 4
    for (int i = 0; i < 64; ++i) {
        float4 hv = *(const float4*)&sHT[i][rg * 4];
        float4 fv = *(const float4*)&sFC[i][kg * 4];
        const float* fp = (const float*)&fv;
        #pragma unroll
        for (int b = 0; b < 4; ++b) {
            acc[0][b] += hv.x * fp[b];
            acc[1][b] += hv.y * fp[b];
            acc[2][b] += hv.z * fp[b];
            acc[3][b] += hv.w * fp[b];
        }
    }
    #pragma unroll
    for (int a = 0; a < 4; ++a) {
        int b = r0 + rg * 4 + a;
        int c = b >> 10, n = b & 1023;
        float4 vv = {acc[a][0], acc[a][1], acc[a][2], acc[a][3]};
        *(float4*)(feat + (size_t)c * 786432 + (size_t)tt * 262144 + n * 256 + kh * 128 + kg * 4) = vv;
    }
}

// ---------------- remap + masks + attention logit partials + fd(bf16) ----------------
// grid 8192 (c*1024+n2), block 256.  thread t: h=t>>6 (wave id), f=t&63
__global__ void __launch_bounds__(256) k_remap(const float* __restrict__ feat,
                        const float* __restrict__ attn_src, const float* __restrict__ attn_dst,
                        const float* __restrict__ msrc, const float* __restrict__ mdst,
                        ushort* __restrict__ fd, float* __restrict__ a_src, float* __restrict__ a_dst) {
    int b = blockIdx.x;
    int c = b >> 10, n2 = b & 1023;
    int t = threadIdx.x;
    int h = t >> 6, f = t & 63;
    float md = mdst[b], ms = msrc[b];
    const float* fp = feat + (size_t)c * 786432 + (size_t)n2 * 768;
    float ssum = 0.f, dsum = 0.f;
    #pragma unroll
    for (int t2 = 0; t2 < 3; ++t2) {
        float val = fp[t2 * 256 + t];
        int j = t2 * 64 + f;
        ssum += val * attn_src[h * 192 + j];
        dsum += val * attn_dst[h * 192 + j];
        fd[((size_t)(c * 4 + h) * 1024 + n2) * 192 + j] = f2bfu(val * md);
    }
    #pragma unroll
    for (int o = 32; o > 0; o >>= 1) {
        ssum += __shfl_down(ssum, o, 64);
        dsum += __shfl_down(dsum, o, 64);
    }
    if (f == 0) {
        a_src[(b << 2) + h] = ssum * ms;
        a_dst[(b << 2) + h] = dsum * md;
    }
}

// ---------------- transpose fd[ch][u][j] -> fdt[ch][j][u] (bf16) ----------------
// grid (16 u-tiles, 3 j-tiles, 32 ch), block 256, 64x64 tiles
__global__ void k_trans(const ushort* __restrict__ fd, ushort* __restrict__ fdt) {
    __shared__ ushort tile[64][68];
    int ch = blockIdx.z;
    int u0 = blockIdx.x * 64, j0 = blockIdx.y * 64;
    int t = threadIdx.x;
    const ushort* src = fd + (size_t)ch * (1024 * 192) + (size_t)u0 * 192 + j0;
    #pragma unroll
    for (int i = 0; i < 2; ++i) {
        int vid = t + 256 * i;
        int r = vid >> 3, ccol = (vid & 7) * 8;
        uint4 v = *(const uint4*)(src + (size_t)r * 192 + ccol);
        const ushort* us = (const ushort*)&v;
        #pragma unroll
        for (int jj = 0; jj < 8; ++jj) tile[r][ccol + jj] = us[jj];
    }
    __syncthreads();
    ushort* dst = fdt + (size_t)ch * (192 * 1024) + (size_t)j0 * 1024 + u0;
    #pragma unroll
    for (int i = 0; i < 2; ++i) {
        int vid = t + 256 * i;
        int jr = vid >> 3, uc = (vid & 7) * 8;
        ushort tmp[8];
        #pragma unroll
        for (int jj = 0; jj < 8; ++jj) tmp[jj] = tile[uc + jj][jr];
        *(uint4*)(dst + (size_t)jr * 1024 + uc) = *(const uint4*)tmp;
    }
}

// ---------------- attention + softmax over c; writes a (f32, d_out) and Abuf[ch][v][u] bf16 ----------------
// grid (1024 v, 2 u-chunks), block 256; thread handles u0 = chunk*512 + t*2 and u0+1
// 3-pass recompute softmax: no per-thread logit array -> no scratch spill.
__global__ void __launch_bounds__(256) k_att(const float* __restrict__ a_src,
                                             const float* __restrict__ a_dst,
                                             float* __restrict__ a_out, ushort* __restrict__ Abuf) {
    __shared__ float sAS[32];
    int v = blockIdx.x;
    int t = threadIdx.x;
    if (t < 32) sAS[t] = a_src[((t >> 2) * 1024 + v) * 4 + (t & 3)];
    __syncthreads();
    int u0 = blockIdx.y * 512 + t * 2;

    // ---- pass 1: raw max over c (leaky/clip applied once afterwards) ----
    float mx0[4], mx1[4];
    #pragma unroll
    for (int h = 0; h < 4; ++h) { mx0[h] = -1e30f; mx1[h] = -1e30f; }
    #pragma unroll
    for (int c = 0; c < 8; ++c) {
        float4 d0 = *(const float4*)(a_dst + ((c << 10) + u0) * 4);
        float4 d1 = *(const float4*)(a_dst + ((c << 10) + u0 + 1) * 4);
        const float* dp0 = (const float*)&d0;
        const float* dp1 = (const float*)&d1;
        #pragma unroll
        for (int h = 0; h < 4; ++h) {
            float as = sAS[c * 4 + h];
            mx0[h] = fmaxf(mx0[h], as + dp0[h]);
            mx1[h] = fmaxf(mx1[h], as + dp1[h]);
        }
    }
    #pragma unroll
    for (int h = 0; h < 4; ++h) {
        float x = mx0[h];
        x = (x >= 0.f) ? x : NEG_SLOPE * x;
        mx0[h] = fminf(fmaxf(x, -1e9f), 1e9f);
        float y = mx1[h];
        y = (y >= 0.f) ? y : NEG_SLOPE * y;
        mx1[h] = fminf(fmaxf(y, -1e9f), 1e9f);
    }

    // ---- pass 2: recompute logits, accumulate exp sums ----
    float s0[4] = {0.f, 0.f, 0.f, 0.f}, s1[4] = {0.f, 0.f, 0.f, 0.f};
    #pragma unroll
    for (int c = 0; c < 8; ++c) {
        float4 d0 = *(const float4*)(a_dst + ((c << 10) + u0) * 4);
        float4 d1 = *(const float4*)(a_dst + ((c << 10) + u0 + 1) * 4);
        const float* dp0 = (const float*)&d0;
        const float* dp1 = (const float*)&d1;
        #pragma unroll
        for (int h = 0; h < 4; ++h) {
            float as = sAS[c * 4 + h];
            float x = as + dp0[h];
            x = (x >= 0.f) ? x : NEG_SLOPE * x;
            x = fminf(fmaxf(x, -1e9f), 1e9f);
            s0[h] += __expf(x - mx0[h]);
            float y = as + dp1[h];
            y = (y >= 0.f) ? y : NEG_SLOPE * y;
            y = fminf(fmaxf(y, -1e9f), 1e9f);
            s1[h] += __expf(y - mx1[h]);
        }
    }
    float r0[4], r1[4];
    #pragma unroll
    for (int h = 0; h < 4; ++h) { r0[h] = 1.f / s0[h]; r1[h] = 1.f / s1[h]; }

    // ---- pass 3: recompute, normalize, write a_out (f32) + Abuf (bf16) ----
    #pragma unroll
    for (int c = 0; c < 8; ++c) {
        float4 d0 = *(const float4*)(a_dst + ((c << 10) + u0) * 4);
        float4 d1 = *(const float4*)(a_dst + ((c << 10) + u0 + 1) * 4);
        const float* dp0 = (const float*)&d0;
        const float* dp1 = (const float*)&d1;
        float w0[4], w1[4];
        unsigned packs[4];
        #pragma unroll
        for (int h = 0; h < 4; ++h) {
            float as = sAS[c * 4 + h];
            float x = as + dp0[h];
            x = (x >= 0.f) ? x : NEG_SLOPE * x;
            x = fminf(fmaxf(x, -1e9f), 1e9f);
            float p0 = __expf(x - mx0[h]) * r0[h];
            float y = as + dp1[h];
            y = (y >= 0.f) ? y : NEG_SLOPE * y;
            y = fminf(fmaxf(y, -1e9f), 1e9f);
            float p1 = __expf(y - mx1[h]) * r1[h];
            w0[h] = p0; w1[h] = p1;
            packs[h] = (unsigned)f2bfu(p0) | ((unsigned)f2bfu(p1) << 16);
        }
        float* ao = a_out + ((size_t)((c << 10) + v) * 1024 + u0) * 4;
        *(float4*)ao = *(const float4*)w0;
        *((float4*)ao + 1) = *(const float4*)w1;
        #pragma unroll
        for (int h = 0; h < 4; ++h)
            *(unsigned*)(Abuf + (size_t)((c * 4 + h) * 1024 + v) * 1024 + u0) = packs[h];
    }
}

// ---------------- GEMM per (c,h): M[v][j] = sum_u A[v][u] * fdt[j][u] ----------------
// grid (16 v-tiles, 32 ch) = 512 blocks, block 256 (4 waves). BM=64, BN=192, BK=64.
// 2 blocks/CU -> 8 waves/CU: staging latency of one block hides under the other's MFMA.
// Waves split N: wave wid covers cols wid*48..+48 (3x16), full 64 rows (4x16).
__global__ void __launch_bounds__(256) k_gemm(const ushort* __restrict__ A,
                                              const ushort* __restrict__ B,
                                              float* __restrict__ Mout) {
    __shared__ ushort sA[64 * 72];
    __shared__ ushort sB[192 * 72];
    int ch = blockIdx.y;
    int v0 = blockIdx.x * 64;
    int t = threadIdx.x;
    const ushort* pA = A + (size_t)ch * (1024 * 1024) + (size_t)v0 * 1024;
    const ushort* pB = B + (size_t)ch * (192 * 1024);
    int wid = t >> 6, lane = t & 63;
    int wn = wid * 48;
    int lm = lane & 15, lq = lane >> 4;
    f32x4 acc[4][3];
    #pragma unroll
    for (int i = 0; i < 4; ++i)
        #pragma unroll
        for (int j = 0; j < 3; ++j)
            acc[i][j] = (f32x4){0.f, 0.f, 0.f, 0.f};
    for (int kk = 0; kk < 1024; kk += 64) {
        #pragma unroll
        for (int i = 0; i < 2; ++i) {
            int cid = t + 256 * i;
            int r = cid >> 3, kc = cid & 7;
            uint4 vv = *(const uint4*)(pA + (size_t)r * 1024 + kk + kc * 8);
            *(uint4*)&sA[r * 72 + kc * 8] = vv;
        }
        #pragma unroll
        for (int i = 0; i < 6; ++i) {
            int cid = t + 256 * i;
            int r = cid >> 3, kc = cid & 7;
            uint4 vv = *(const uint4*)(pB + (size_t)r * 1024 + kk + kc * 8);
            *(uint4*)&sB[r * 72 + kc * 8] = vv;
        }
        __syncthreads();
        #pragma unroll
        for (int ks = 0; ks < 64; ks += 32) {
            bf16x8 af[4], bg[3];
            #pragma unroll
            for (int i = 0; i < 4; ++i)
                af[i] = *(const bf16x8*)&sA[(i * 16 + lm) * 72 + ks + lq * 8];
            #pragma unroll
            for (int j = 0; j < 3; ++j)
                bg[j] = *(const bf16x8*)&sB[(wn + j * 16 + lm) * 72 + ks + lq * 8];
            #pragma unroll
            for (int i = 0; i < 4; ++i)
                #pragma unroll
                for (int j = 0; j < 3; ++j)
                    acc[i][j] = __builtin_amdgcn_mfma_f32_16x16x32_bf16(af[i], bg[j], acc[i][j], 0, 0, 0);
        }
        __syncthreads();
    }
    float* pM = Mout + (size_t)ch * 196608 + (size_t)v0 * 192;
    #pragma unroll
    for (int i = 0; i < 4; ++i)
        #pragma unroll
        for (int r = 0; r < 4; ++r) {
            int row = i * 16 + lq * 4 + r;
            #pragma unroll
            for (int j = 0; j < 3; ++j)
                pM[(size_t)row * 192 + wn + j * 16 + lm] = acc[i][j][r];
        }
}

// ---------------- epilogue: outs[c][v][tf] = sum_h relu(M[ch][v][tf]) (f32) ----------------
__global__ void k_out(const float* __restrict__ Mm, float* __restrict__ outp) {
    int b = blockIdx.x;
    int c = b >> 10, v = b & 1023;
    int tf = threadIdx.x;
    float s = 0.f;
    #pragma unroll
    for (int h = 0; h < 4; ++h) {
        float x = Mm[(size_t)(c * 4 + h) * 196608 + (size_t)v * 192 + tf];
        s += fmaxf(x, 0.f);
    }
    outp[(size_t)b * 192 + tf] = s;
}

extern "C" void kernel_launch(void* const* d_in, const int* in_sizes, int n_in,
                              void* d_out, int out_size, void* d_ws, size_t ws_size,
                              hipStream_t stream) {
    const int*   edges  = (const int*)d_in[0];
    const float* nf     = (const float*)d_in[1];
    const float* fc     = (const float*)d_in[2];
    const float* asrc_w = (const float*)d_in[3];
    const float* adst_w = (const float*)d_in[4];
    float* outp  = (float*)d_out;
    float* a_out = outp + 1572864;     // outs (1,572,864 f32) then a (33,554,432 f32)

    char* ws = (char*)d_ws;
    float*  msrc  = (float*)(ws + 0);            // 32 KB
    float*  mdst  = (float*)(ws + 32768);        // 32 KB
    float*  a_src = (float*)(ws + 65536);        // 128 KB
    float*  a_dst = (float*)(ws + 196608);       // 128 KB
    ushort* fdt   = (ushort*)(ws + 327680);      // 12.58 MB bf16
    float*  feat  = (float*)(ws + 12910592);     // 25.17 MB f32 (aliased with Mm)
    float*  Mm    = feat;                        // feat dead after k_remap
    ushort* Abuf  = (ushort*)(ws + 38076416);    // 67.1 MB bf16
    ushort* fd    = Abuf;                        // fd dead after k_trans, before k_att writes Abuf

    hipMemsetAsync(msrc, 0, 65536, stream);      // zero both masks
    k_scatter<<<dim3(256), dim3(256), 0, stream>>>(edges, msrc, mdst);
    k_feat<<<dim3(512, 3), dim3(256), 0, stream>>>(nf, fc, feat);
    k_remap<<<dim3(8192), dim3(256), 0, stream>>>(feat, asrc_w, adst_w, msrc, mdst, fd, a_src, a_dst);
    k_trans<<<dim3(16, 3, 32), dim3(256), 0, stream>>>(fd, fdt);
    k_att<<<dim3(1024, 2), dim3(256), 0, stream>>>(a_src, a_dst, a_out, Abuf);
    k_gemm<<<dim3(16, 32), dim3(256), 0, stream>>>(Abuf, fdt, Mm);
    k_out<<<dim3(8192), dim3(192), 0, stream>>>(Mm, outp);
}